// Round 5
// baseline (401.380 us; speedup 1.0000x reference)
//
#include <hip/hip_runtime.h>
#include <hip/hip_bf16.h>
#include <math.h>

#define NNODES 8192
#define DIM 128
#define SMAX 128
#define HSIZE 16384   // hash table capacity (power of 2)
#define NB 512        // mega-kernel blocks (2/CU on 256 CUs -> always co-resident)
#define NT 256

// Per-thread index-dtype detection: reads first 4 int64-interpretations of row.
__device__ __forceinline__ int detect64(const void* rowp) {
    const long long* p = (const long long*)rowp;
    int is64 = 1;
#pragma unroll
    for (int i = 0; i < 4; i++) {
        long long v = p[i];
        if (v < 0 || v >= NNODES) is64 = 0;
    }
    return is64;
}

__device__ __forceinline__ int edge_idx(const void* p, int e, int idx64) {
    if (idx64) return (int)((const long long*)p)[e];
    return ((const int*)p)[e];
}

__device__ __forceinline__ int hash_insert(unsigned int* hashK, unsigned int key1) {
    unsigned int h = (key1 * 2654435761u) & (HSIZE - 1);
    for (;;) {
        unsigned int prev = atomicCAS(&hashK[h], 0u, key1);
        if (prev == 0u || prev == key1) return (int)h;
        h = (h + 1) & (HSIZE - 1);
    }
}

__device__ __forceinline__ int hash_find(const unsigned int* hashK, unsigned int key1) {
    unsigned int h = (key1 * 2654435761u) & (HSIZE - 1);
    for (;;) {
        unsigned int k = hashK[h];
        if (k == key1) return (int)h;
        h = (h + 1) & (HSIZE - 1);
    }
}

// One-shot grid barrier: counter pre-zeroed by k_zero, used exactly once.
__device__ __forceinline__ void gbar(int* ctr) {
    __syncthreads();
    if (threadIdx.x == 0) {
        __threadfence();   // release: flush this XCD's L2 for prior writes
        __hip_atomic_fetch_add(ctr, 1, __ATOMIC_ACQ_REL, __HIP_MEMORY_SCOPE_AGENT);
        while (__hip_atomic_load(ctr, __ATOMIC_ACQUIRE, __HIP_MEMORY_SCOPE_AGENT) < NB)
            __builtin_amdgcn_s_sleep(1);
        __threadfence();   // acquire: invalidate stale lines before reads
    }
    __syncthreads();
}

// --- K0: zero scratch (custom: rocclr fillBuffer is ~39us even for 353KB) ---
__global__ __launch_bounds__(256) void k_zero(float4* z, int n4) {
    int i = blockIdx.x * blockDim.x + threadIdx.x;
    if (i < n4) z[i] = make_float4(0.f, 0.f, 0.f, 0.f);
}

// --- K1: everything else, phase-separated by one-shot global barriers ---
__global__ __launch_bounds__(NT) void k_mega(
        const float* x, const float* embed, const float* adjd, const float* noise,
        const float* tmp, const float* W1e, const float* b1e, const float* W2e,
        const float* b2e, const float* Wg0, const float* Wg1,
        const void* rowp, const void* colp, const int* nodep,
        float* U, float* V, float* xw, float* cself,
        int* flags, float* cnt0, float* cnt0n, int* slotmap,
        unsigned int* list, unsigned int* hashK, float* hashC,
        float* hashF, float* hashR, float* f0s, float* r0s,
        float* h1acc, int* bar, float* out, int E) {
    int bid = blockIdx.x;
    int t = threadIdx.x;
    int gid = bid * NT + t;
    int idx64 = detect64(rowp);
    int nodeid = nodep[0];

    __shared__ float sm[16][DIM];

    // ================= Phase A: dense precompute + nodeid mark-scan ========
    // tiles: [0,512) U/V (16 embed rows each); [512,1024) xw (16 x rows); 1024 cself
    for (int tile = bid; tile < 1025; tile += NB) {
        if (tile < 512) {
            int n0 = tile * 16;
            for (int i = t; i < 16 * DIM; i += NT)
                sm[i >> 7][i & 127] = embed[(size_t)n0 * DIM + i];
            __syncthreads();
            int sub = t >> 7;            // row group 0-7 / 8-15
            int q = (t >> 6) & 1;        // 0 -> U, 1 -> V
            int lane = t & 63;
            const float* Wc = W1e + (size_t)q * DIM * 64;
            float acc[8] = {0};
            for (int d = 0; d < DIM; d++) {
                float w = Wc[d * 64 + lane];
#pragma unroll
                for (int i = 0; i < 8; i++) acc[i] += sm[sub * 8 + i][d] * w;
            }
            float* o = q ? V : U;
            for (int i = 0; i < 8; i++)
                o[(size_t)(n0 + sub * 8 + i) * 64 + lane] = acc[i];
            __syncthreads();
        } else if (tile < 1024) {
            int n0 = (tile - 512) * 16;
            for (int i = t; i < 16 * DIM; i += NT)
                sm[i >> 7][i & 127] = x[(size_t)n0 * DIM + i];
            __syncthreads();
            int col = t & 127;
            int half = t >> 7;
            float acc[8] = {0};
            for (int d = 0; d < DIM; d++) {
                float w = Wg0[d * DIM + col];
#pragma unroll
                for (int i = 0; i < 8; i++) acc[i] += sm[half * 8 + i][d] * w;
            }
            for (int i = 0; i < 8; i++)
                xw[(size_t)(n0 + half * 8 + i) * DIM + col] = acc[i];
            __syncthreads();
        } else {
            if (t < DIM) sm[0][t] = embed[(size_t)nodeid * DIM + t];
            __syncthreads();
            if (t < 64) {
                float a = b1e[t];
                for (int d = 0; d < DIM; d++)
                    a += sm[0][d] * W1e[(2 * DIM + d) * 64 + t];
                cself[t] = a;
            }
            __syncthreads();
        }
    }
    // mark out-neighbors of nodeid
    for (int e = gid; e < E; e += NB * NT) {
        int r = edge_idx(rowp, e, idx64);
        if (r != nodeid) continue;
        int c = edge_idx(colp, e, idx64);
        if (c == nodeid) continue;
        atomicAdd(&cnt0[c], adjd[e]);
    }
    gbar(&bar[0]);

    // ================= Phase B: compact neighbors into slots ===============
    if (gid < NNODES) {
        int n = gid;
        int smv = -1;
        if (n != nodeid && cnt0[n] > 0.f) {
            int s = atomicAdd(&flags[1], 1);
            if (s < SMAX) {
                cnt0n[s] = cnt0[n];
                smv = s;
            }
        }
        slotmap[n] = smv;
    }
    gbar(&bar[1]);

    // ================= Phase C: classify edges, hash-insert, list ==========
    for (int e = gid; e < E; e += NB * NT) {
        int r = edge_idx(rowp, e, idx64);
        int c = edge_idx(colp, e, idx64);
        if (r == c) continue;
        int sr = slotmap[r];
        int sc = slotmap[c];
        int f = 0;
        if (sr >= 0) {
            f |= 1;
            unsigned int key1 = ((unsigned int)(sr << 13) | (unsigned int)c) + 1u;
            int idx = hash_insert(hashK, key1);
            atomicAdd(&hashC[idx], adjd[e]);
        }
        if (sc >= 0) {
            f |= 2;
            unsigned int key1 = ((unsigned int)(sc << 13) | (unsigned int)r) + 1u;
            hash_insert(hashK, key1);
        }
        if (r == nodeid && sc >= 0) f |= 4;
        if (c == nodeid && sr >= 0) f |= 8;
        if (f) {
            int pos = atomicAdd(&flags[2], 1);
            list[pos] = (unsigned int)e | ((unsigned int)f << 28);
        }
    }
    gbar(&bar[2]);

    // ================= Phase D: gate MLP for listed edges ==================
    {
        int ncnt = flags[2];
        int wv = gid >> 6;
        int lane = t & 63;
        int nwv = (NB * NT) >> 6;
        float w2 = W2e[lane];
        float cs = cself[lane];
        float beta = tmp[0];
        float b2 = b2e[0];
        for (int i = wv; i < ncnt; i += nwv) {
            unsigned int u = list[i];
            int e = (int)(u & 0x0FFFFFFFu);
            int f = (int)(u >> 28);
            int r = edge_idx(rowp, e, idx64);
            int c = edge_idx(colp, e, idx64);
            float h = U[(size_t)r * 64 + lane] + V[(size_t)c * 64 + lane] + cs;
            h = h > 0.f ? h : 0.f;
            float p = h * w2;
            for (int o = 32; o >= 1; o >>= 1) p += __shfl_xor(p, o, 64);
            if (lane == 0) {
                float la = p + b2;
                float nz = noise[e];
                float gi = (logf(nz) - log1pf(-nz) + la) / beta;
                float v = 1.f / (1.f + expf(-gi));
                if (f & 1) {
                    unsigned int key1 = ((unsigned int)(slotmap[r] << 13) | (unsigned int)c) + 1u;
                    atomicAdd(&hashF[hash_find(hashK, key1)], v);
                }
                if (f & 2) {
                    unsigned int key1 = ((unsigned int)(slotmap[c] << 13) | (unsigned int)r) + 1u;
                    atomicAdd(&hashR[hash_find(hashK, key1)], v);
                }
                if (f & 4) atomicAdd(&f0s[slotmap[c]], v);
                if (f & 8) atomicAdd(&r0s[slotmap[r]], v);
            }
        }
    }
    gbar(&bar[3]);

    // ================= Phase E: hash-aggregate into h1acc ==================
    {
        int group = gid >> 7;                 // 128-thread groups
        int tg = t & 127;
        int ngroups = (NB * NT) >> 7;
        for (int entry = group; entry < HSIZE; entry += ngroups) {
            unsigned int key1 = hashK[entry];
            if (key1 == 0u) continue;
            float wgt = hashC[entry] * (hashF[entry] + hashR[entry]) * 0.5f;
            if (wgt == 0.f) continue;
            unsigned int key = key1 - 1u;
            int s = (int)(key >> 13);
            int k = (int)(key & 8191u);
            atomicAdd(&h1acc[(size_t)s * DIM + tg], wgt * xw[(size_t)k * DIM + tg]);
        }
    }
    gbar(&bar[4]);

    // ================= Phase F: final reduce + softmax (block 0) ===========
    if (bid != 0) return;
    __shared__ float sacc[7];
    if (t < 7) sacc[t] = 0.f;
    __syncthreads();
    int ns = flags[1]; if (ns > SMAX) ns = SMAX;
    int wave = t >> 6, lane = t & 63;
    for (int s = wave; s < ns; s += 4) {
        float a0 = cnt0n[s] * (f0s[s] + r0s[s]) * 0.5f;
        float v0 = h1acc[(size_t)s * DIM + lane];
        float v1 = h1acc[(size_t)s * DIM + lane + 64];
        v0 = v0 > 0.f ? v0 : 0.f;
        v1 = v1 > 0.f ? v1 : 0.f;
        float part[7];
        for (int c = 0; c < 7; c++) {
            float p = v0 * Wg1[lane * 7 + c] + v1 * Wg1[(lane + 64) * 7 + c];
            for (int o = 32; o >= 1; o >>= 1) p += __shfl_xor(p, o, 64);
            part[c] = p;
        }
        if (lane == 0)
            for (int c = 0; c < 7; c++) atomicAdd(&sacc[c], a0 * part[c]);
    }
    __syncthreads();
    if (t == 0) {
        float v[7], m = -1e30f, ssum = 0.f;
        for (int c = 0; c < 7; c++) { v[c] = sacc[c]; if (v[c] > m) m = v[c]; }
        for (int c = 0; c < 7; c++) { v[c] = expf(v[c] - m); ssum += v[c]; }
        for (int c = 0; c < 7; c++) out[c] = v[c] / ssum;
    }
}

extern "C" void kernel_launch(void* const* d_in, const int* in_sizes, int n_in,
                              void* d_out, int out_size, void* d_ws, size_t ws_size,
                              hipStream_t stream) {
    const float* x     = (const float*)d_in[0];
    const float* embed = (const float*)d_in[1];
    const float* adjd  = (const float*)d_in[2];
    const float* noise = (const float*)d_in[3];
    const float* tmp   = (const float*)d_in[4];
    const float* W1e   = (const float*)d_in[5];
    const float* b1e   = (const float*)d_in[6];
    const float* W2e   = (const float*)d_in[7];
    const float* b2e   = (const float*)d_in[8];
    const float* Wg0   = (const float*)d_in[9];
    const float* Wg1   = (const float*)d_in[10];
    const void*  rowp  = d_in[11];
    const void*  colp  = d_in[12];
    const int*   nodep = (const int*)d_in[13];
    int E = in_sizes[3];   // noise is float32[E]

    char* w = (char*)d_ws;
    size_t off = 0;
    auto alloc = [&](size_t bytes) -> char* {
        char* p = w + off;
        off = (off + bytes + 255) & ~(size_t)255;
        return p;
    };
    float*        cself   = (float*)alloc(64 * 4);
    float*        cnt0n   = (float*)alloc(SMAX * 4);
    int*          slotmap = (int*)  alloc((size_t)NNODES * 4);
    float*        U       = (float*)alloc((size_t)NNODES * 64 * 4);
    float*        V       = (float*)alloc((size_t)NNODES * 64 * 4);
    float*        xw      = (float*)alloc((size_t)NNODES * DIM * 4);
    unsigned int* list    = (unsigned int*)alloc((size_t)E * 4);
    char*         zstart  = w + off;
    int*          flags   = (int*)  alloc(256);
    int*          bar     = (int*)  alloc(256);
    float*        cnt0    = (float*)alloc((size_t)NNODES * 4);
    float*        f0s     = (float*)alloc(SMAX * 4);
    float*        r0s     = (float*)alloc(SMAX * 4);
    unsigned int* hashK   = (unsigned int*)alloc((size_t)HSIZE * 4);
    float*        hashC   = (float*)alloc((size_t)HSIZE * 4);
    float*        hashF   = (float*)alloc((size_t)HSIZE * 4);
    float*        hashR   = (float*)alloc((size_t)HSIZE * 4);
    float*        h1acc   = (float*)alloc((size_t)SMAX * DIM * 4);
    size_t zbytes  = (size_t)((w + off) - zstart);
    int n4 = (int)(zbytes / 16);

    k_zero<<<(n4 + 255) / 256, 256, 0, stream>>>((float4*)zstart, n4);
    k_mega<<<NB, NT, 0, stream>>>(x, embed, adjd, noise, tmp, W1e, b1e, W2e, b2e,
                                  Wg0, Wg1, rowp, colp, nodep,
                                  U, V, xw, cself, flags, cnt0, cnt0n, slotmap,
                                  list, hashK, hashC, hashF, hashR, f0s, r0s,
                                  h1acc, bar, (float*)d_out, E);
}

// Round 6
// 230.680 us; speedup vs baseline: 1.7400x; 1.7400x over previous
//
#include <hip/hip_runtime.h>
#include <hip/hip_bf16.h>
#include <math.h>

#define NNODES 8192
#define DIM 128
#define SMAX 128
#define HSIZE 16384   // hash table capacity (power of 2)
#define NB 512        // mega-kernel blocks (2/CU on 256 CUs -> always co-resident)
#define NT 256

// Per-thread index-dtype detection: reads first 4 int64-interpretations of row.
__device__ __forceinline__ int detect64(const void* rowp) {
    const long long* p = (const long long*)rowp;
    int is64 = 1;
#pragma unroll
    for (int i = 0; i < 4; i++) {
        long long v = p[i];
        if (v < 0 || v >= NNODES) is64 = 0;
    }
    return is64;
}

__device__ __forceinline__ int edge_idx(const void* p, int e, int idx64) {
    if (idx64) return (int)((const long long*)p)[e];
    return ((const int*)p)[e];
}

__device__ __forceinline__ int hash_insert(unsigned int* hashK, unsigned int key1) {
    unsigned int h = (key1 * 2654435761u) & (HSIZE - 1);
    for (;;) {
        unsigned int prev = atomicCAS(&hashK[h], 0u, key1);
        if (prev == 0u || prev == key1) return (int)h;
        h = (h + 1) & (HSIZE - 1);
    }
}

__device__ __forceinline__ int hash_find(const unsigned int* hashK, unsigned int key1) {
    unsigned int h = (key1 * 2654435761u) & (HSIZE - 1);
    for (;;) {
        unsigned int k = hashK[h];
        if (k == key1) return (int)h;
        h = (h + 1) & (HSIZE - 1);
    }
}

// One-shot grid barrier, counter pre-zeroed by k_zero, used exactly once.
// CRITICAL: spin with RELAXED load (no per-poll cache maintenance). An
// ACQUIRE-loaded spin emits buffer_inv every iteration -> 512 blocks strobe
// L2 invalidates and starve the working blocks (measured: 390us kernel).
__device__ __forceinline__ void gbar(int* ctr) {
    __syncthreads();
    if (threadIdx.x == 0) {
        __builtin_amdgcn_fence(__ATOMIC_RELEASE, "agent");   // one writeback
        __hip_atomic_fetch_add(ctr, 1, __ATOMIC_RELAXED, __HIP_MEMORY_SCOPE_AGENT);
        while (__hip_atomic_load(ctr, __ATOMIC_RELAXED, __HIP_MEMORY_SCOPE_AGENT) < NB)
            __builtin_amdgcn_s_sleep(2);                     // ~128cy backoff
        __builtin_amdgcn_fence(__ATOMIC_ACQUIRE, "agent");   // one invalidate
    }
    __syncthreads();
}

// --- K0: zero scratch (custom: rocclr fillBuffer is ~39us even for 353KB) ---
__global__ __launch_bounds__(256) void k_zero(float4* z, int n4) {
    int i = blockIdx.x * blockDim.x + threadIdx.x;
    if (i < n4) z[i] = make_float4(0.f, 0.f, 0.f, 0.f);
}

// --- K1: everything else, phase-separated by one-shot global barriers ---
__global__ __launch_bounds__(NT) void k_mega(
        const float* x, const float* embed, const float* adjd, const float* noise,
        const float* tmp, const float* W1e, const float* b1e, const float* W2e,
        const float* b2e, const float* Wg0, const float* Wg1,
        const void* rowp, const void* colp, const int* nodep,
        float* U, float* V, float* xw, float* cself,
        int* flags, float* cnt0, float* cnt0n, int* slotmap,
        unsigned int* list, unsigned int* hashK, float* hashC,
        float* hashF, float* hashR, float* f0s, float* r0s,
        float* h1acc, int* bar, float* out, int E) {
    int bid = blockIdx.x;
    int t = threadIdx.x;
    int gid = bid * NT + t;
    int idx64 = detect64(rowp);
    int nodeid = nodep[0];

    __shared__ float sm[16][DIM];

    // ================= Phase A: dense precompute + nodeid mark-scan ========
    // tiles: [0,512) U/V (16 embed rows each); [512,1024) xw (16 x rows); 1024 cself
    for (int tile = bid; tile < 1025; tile += NB) {
        if (tile < 512) {
            int n0 = tile * 16;
            for (int i = t; i < 16 * DIM; i += NT)
                sm[i >> 7][i & 127] = embed[(size_t)n0 * DIM + i];
            __syncthreads();
            int sub = t >> 7;            // row group 0-7 / 8-15
            int q = (t >> 6) & 1;        // 0 -> U, 1 -> V
            int lane = t & 63;
            const float* Wc = W1e + (size_t)q * DIM * 64;
            float acc[8] = {0};
            for (int d = 0; d < DIM; d++) {
                float w = Wc[d * 64 + lane];
#pragma unroll
                for (int i = 0; i < 8; i++) acc[i] += sm[sub * 8 + i][d] * w;
            }
            float* o = q ? V : U;
            for (int i = 0; i < 8; i++)
                o[(size_t)(n0 + sub * 8 + i) * 64 + lane] = acc[i];
            __syncthreads();
        } else if (tile < 1024) {
            int n0 = (tile - 512) * 16;
            for (int i = t; i < 16 * DIM; i += NT)
                sm[i >> 7][i & 127] = x[(size_t)n0 * DIM + i];
            __syncthreads();
            int col = t & 127;
            int half = t >> 7;
            float acc[8] = {0};
            for (int d = 0; d < DIM; d++) {
                float w = Wg0[d * DIM + col];
#pragma unroll
                for (int i = 0; i < 8; i++) acc[i] += sm[half * 8 + i][d] * w;
            }
            for (int i = 0; i < 8; i++)
                xw[(size_t)(n0 + half * 8 + i) * DIM + col] = acc[i];
            __syncthreads();
        } else {
            if (t < DIM) sm[0][t] = embed[(size_t)nodeid * DIM + t];
            __syncthreads();
            if (t < 64) {
                float a = b1e[t];
                for (int d = 0; d < DIM; d++)
                    a += sm[0][d] * W1e[(2 * DIM + d) * 64 + t];
                cself[t] = a;
            }
            __syncthreads();
        }
    }
    // mark out-neighbors of nodeid
    for (int e = gid; e < E; e += NB * NT) {
        int r = edge_idx(rowp, e, idx64);
        if (r != nodeid) continue;
        int c = edge_idx(colp, e, idx64);
        if (c == nodeid) continue;
        atomicAdd(&cnt0[c], adjd[e]);
    }
    gbar(&bar[0]);

    // ================= Phase B: compact neighbors into slots ===============
    if (gid < NNODES) {
        int n = gid;
        int smv = -1;
        if (n != nodeid && cnt0[n] > 0.f) {
            int s = atomicAdd(&flags[1], 1);
            if (s < SMAX) {
                cnt0n[s] = cnt0[n];
                smv = s;
            }
        }
        slotmap[n] = smv;
    }
    gbar(&bar[1]);

    // ================= Phase C: classify edges, hash-insert, list ==========
    for (int e = gid; e < E; e += NB * NT) {
        int r = edge_idx(rowp, e, idx64);
        int c = edge_idx(colp, e, idx64);
        if (r == c) continue;
        int sr = slotmap[r];
        int sc = slotmap[c];
        int f = 0;
        if (sr >= 0) {
            f |= 1;
            unsigned int key1 = ((unsigned int)(sr << 13) | (unsigned int)c) + 1u;
            int idx = hash_insert(hashK, key1);
            atomicAdd(&hashC[idx], adjd[e]);
        }
        if (sc >= 0) {
            f |= 2;
            unsigned int key1 = ((unsigned int)(sc << 13) | (unsigned int)r) + 1u;
            hash_insert(hashK, key1);
        }
        if (r == nodeid && sc >= 0) f |= 4;
        if (c == nodeid && sr >= 0) f |= 8;
        if (f) {
            int pos = atomicAdd(&flags[2], 1);
            list[pos] = (unsigned int)e | ((unsigned int)f << 28);
        }
    }
    gbar(&bar[2]);

    // ================= Phase D: gate MLP for listed edges ==================
    {
        int ncnt = flags[2];
        int wv = gid >> 6;
        int lane = t & 63;
        int nwv = (NB * NT) >> 6;
        float w2 = W2e[lane];
        float cs = cself[lane];
        float beta = tmp[0];
        float b2 = b2e[0];
        for (int i = wv; i < ncnt; i += nwv) {
            unsigned int u = list[i];
            int e = (int)(u & 0x0FFFFFFFu);
            int f = (int)(u >> 28);
            int r = edge_idx(rowp, e, idx64);
            int c = edge_idx(colp, e, idx64);
            float h = U[(size_t)r * 64 + lane] + V[(size_t)c * 64 + lane] + cs;
            h = h > 0.f ? h : 0.f;
            float p = h * w2;
            for (int o = 32; o >= 1; o >>= 1) p += __shfl_xor(p, o, 64);
            if (lane == 0) {
                float la = p + b2;
                float nz = noise[e];
                float gi = (logf(nz) - log1pf(-nz) + la) / beta;
                float v = 1.f / (1.f + expf(-gi));
                if (f & 1) {
                    unsigned int key1 = ((unsigned int)(slotmap[r] << 13) | (unsigned int)c) + 1u;
                    atomicAdd(&hashF[hash_find(hashK, key1)], v);
                }
                if (f & 2) {
                    unsigned int key1 = ((unsigned int)(slotmap[c] << 13) | (unsigned int)r) + 1u;
                    atomicAdd(&hashR[hash_find(hashK, key1)], v);
                }
                if (f & 4) atomicAdd(&f0s[slotmap[c]], v);
                if (f & 8) atomicAdd(&r0s[slotmap[r]], v);
            }
        }
    }
    gbar(&bar[3]);

    // ================= Phase E: hash-aggregate into h1acc ==================
    {
        int group = gid >> 7;                 // 128-thread groups
        int tg = t & 127;
        int ngroups = (NB * NT) >> 7;
        for (int entry = group; entry < HSIZE; entry += ngroups) {
            unsigned int key1 = hashK[entry];
            if (key1 == 0u) continue;
            float wgt = hashC[entry] * (hashF[entry] + hashR[entry]) * 0.5f;
            if (wgt == 0.f) continue;
            unsigned int key = key1 - 1u;
            int s = (int)(key >> 13);
            int k = (int)(key & 8191u);
            atomicAdd(&h1acc[(size_t)s * DIM + tg], wgt * xw[(size_t)k * DIM + tg]);
        }
    }
    gbar(&bar[4]);

    // ================= Phase F: final reduce + softmax (block 0) ===========
    if (bid != 0) return;
    __shared__ float sacc[7];
    if (t < 7) sacc[t] = 0.f;
    __syncthreads();
    int ns = flags[1]; if (ns > SMAX) ns = SMAX;
    int wave = t >> 6, lane = t & 63;
    for (int s = wave; s < ns; s += 4) {
        float a0 = cnt0n[s] * (f0s[s] + r0s[s]) * 0.5f;
        float v0 = h1acc[(size_t)s * DIM + lane];
        float v1 = h1acc[(size_t)s * DIM + lane + 64];
        v0 = v0 > 0.f ? v0 : 0.f;
        v1 = v1 > 0.f ? v1 : 0.f;
        float part[7];
        for (int c = 0; c < 7; c++) {
            float p = v0 * Wg1[lane * 7 + c] + v1 * Wg1[(lane + 64) * 7 + c];
            for (int o = 32; o >= 1; o >>= 1) p += __shfl_xor(p, o, 64);
            part[c] = p;
        }
        if (lane == 0)
            for (int c = 0; c < 7; c++) atomicAdd(&sacc[c], a0 * part[c]);
    }
    __syncthreads();
    if (t == 0) {
        float v[7], m = -1e30f, ssum = 0.f;
        for (int c = 0; c < 7; c++) { v[c] = sacc[c]; if (v[c] > m) m = v[c]; }
        for (int c = 0; c < 7; c++) { v[c] = expf(v[c] - m); ssum += v[c]; }
        for (int c = 0; c < 7; c++) out[c] = v[c] / ssum;
    }
}

extern "C" void kernel_launch(void* const* d_in, const int* in_sizes, int n_in,
                              void* d_out, int out_size, void* d_ws, size_t ws_size,
                              hipStream_t stream) {
    const float* x     = (const float*)d_in[0];
    const float* embed = (const float*)d_in[1];
    const float* adjd  = (const float*)d_in[2];
    const float* noise = (const float*)d_in[3];
    const float* tmp   = (const float*)d_in[4];
    const float* W1e   = (const float*)d_in[5];
    const float* b1e   = (const float*)d_in[6];
    const float* W2e   = (const float*)d_in[7];
    const float* b2e   = (const float*)d_in[8];
    const float* Wg0   = (const float*)d_in[9];
    const float* Wg1   = (const float*)d_in[10];
    const void*  rowp  = d_in[11];
    const void*  colp  = d_in[12];
    const int*   nodep = (const int*)d_in[13];
    int E = in_sizes[3];   // noise is float32[E]

    char* w = (char*)d_ws;
    size_t off = 0;
    auto alloc = [&](size_t bytes) -> char* {
        char* p = w + off;
        off = (off + bytes + 255) & ~(size_t)255;
        return p;
    };
    float*        cself   = (float*)alloc(64 * 4);
    float*        cnt0n   = (float*)alloc(SMAX * 4);
    int*          slotmap = (int*)  alloc((size_t)NNODES * 4);
    float*        U       = (float*)alloc((size_t)NNODES * 64 * 4);
    float*        V       = (float*)alloc((size_t)NNODES * 64 * 4);
    float*        xw      = (float*)alloc((size_t)NNODES * DIM * 4);
    unsigned int* list    = (unsigned int*)alloc((size_t)E * 4);
    char*         zstart  = w + off;
    int*          flags   = (int*)  alloc(256);
    int*          bar     = (int*)  alloc(256);
    float*        cnt0    = (float*)alloc((size_t)NNODES * 4);
    float*        f0s     = (float*)alloc(SMAX * 4);
    float*        r0s     = (float*)alloc(SMAX * 4);
    unsigned int* hashK   = (unsigned int*)alloc((size_t)HSIZE * 4);
    float*        hashC   = (float*)alloc((size_t)HSIZE * 4);
    float*        hashF   = (float*)alloc((size_t)HSIZE * 4);
    float*        hashR   = (float*)alloc((size_t)HSIZE * 4);
    float*        h1acc   = (float*)alloc((size_t)SMAX * DIM * 4);
    size_t zbytes  = (size_t)((w + off) - zstart);
    int n4 = (int)(zbytes / 16);

    k_zero<<<(n4 + 255) / 256, 256, 0, stream>>>((float4*)zstart, n4);
    k_mega<<<NB, NT, 0, stream>>>(x, embed, adjd, noise, tmp, W1e, b1e, W2e, b2e,
                                  Wg0, Wg1, rowp, colp, nodep,
                                  U, V, xw, cself, flags, cnt0, cnt0n, slotmap,
                                  list, hashK, hashC, hashF, hashR, f0s, r0s,
                                  h1acc, bar, (float*)d_out, E);
}

// Round 7
// 86.124 us; speedup vs baseline: 4.6605x; 2.6785x over previous
//
#include <hip/hip_runtime.h>
#include <hip/hip_bf16.h>
#include <math.h>

#define NNODES 8192
#define DIM 128
#define SMAX 128
#define HSIZE 16384   // hash table capacity (power of 2)
#define NB 256        // 1 block/CU -> co-resident; NB must equal NT (barrier map)
#define NT 256
#define NBAR 3

// Per-thread index-dtype detection: reads first 4 int64-interpretations of row.
__device__ __forceinline__ int detect64(const void* rowp) {
    const long long* p = (const long long*)rowp;
    int is64 = 1;
#pragma unroll
    for (int i = 0; i < 4; i++) {
        long long v = p[i];
        if (v < 0 || v >= NNODES) is64 = 0;
    }
    return is64;
}

__device__ __forceinline__ int edge_idx(const void* p, int e, int idx64) {
    if (idx64) return (int)((const long long*)p)[e];
    return ((const int*)p)[e];
}

__device__ __forceinline__ int hash_insert(unsigned int* hashK, unsigned int key1) {
    unsigned int h = (key1 * 2654435761u) & (HSIZE - 1);
    for (;;) {
        unsigned int prev = atomicCAS(&hashK[h], 0u, key1);
        if (prev == 0u || prev == key1) return (int)h;
        h = (h + 1) & (HSIZE - 1);
    }
}

// One-shot grid barrier with DISTRIBUTED arrival (pre-zeroed by k_zero).
// Round-6 lesson: single-counter agent-scope fetch_add serializes ~90ns/RMW
// at the coherence point -> 44us/barrier at 512 blocks. Here: per-block
// padded arrival slots (parallel stores), master polls them, single
// read-only release flag for everyone else.
__device__ __forceinline__ void gbar(int* arrive, int* release, int bid, int t) {
    __syncthreads();
    if (bid == 0) {
        if (t > 0 && t < NB) {   // thread t waits for block t's arrival slot
            while (__hip_atomic_load(&arrive[t * 32], __ATOMIC_RELAXED,
                                     __HIP_MEMORY_SCOPE_AGENT) == 0)
                __builtin_amdgcn_s_sleep(1);
        }
        __syncthreads();
        __builtin_amdgcn_fence(__ATOMIC_ACQ_REL, "agent");
        if (t == 0)
            __hip_atomic_store(release, 1, __ATOMIC_RELAXED,
                               __HIP_MEMORY_SCOPE_AGENT);
        __syncthreads();
    } else {
        if (t == 0) {
            __builtin_amdgcn_fence(__ATOMIC_RELEASE, "agent");
            __hip_atomic_store(&arrive[bid * 32], 1, __ATOMIC_RELAXED,
                               __HIP_MEMORY_SCOPE_AGENT);
            while (__hip_atomic_load(release, __ATOMIC_RELAXED,
                                     __HIP_MEMORY_SCOPE_AGENT) == 0)
                __builtin_amdgcn_s_sleep(2);
            __builtin_amdgcn_fence(__ATOMIC_ACQUIRE, "agent");
        }
        __syncthreads();
    }
}

// --- K0: zero scratch (custom: rocclr fillBuffer is ~39us even for small) ---
__global__ __launch_bounds__(256) void k_zero(float4* z, int n4) {
    int i = blockIdx.x * blockDim.x + threadIdx.x;
    if (i < n4) z[i] = make_float4(0.f, 0.f, 0.f, 0.f);
}

// --- K1: whole pipeline, 4 phases, 3 distributed grid barriers ---
__global__ __launch_bounds__(NT) void k_mega(
        const float* x, const float* embed, const float* adjd, const float* noise,
        const float* tmp, const float* W1e, const float* b1e, const float* W2e,
        const float* b2e, const float* Wg0, const float* Wg1,
        const void* rowp, const void* colp, const int* nodep,
        float* U, float* V, float* xw, float* cself,
        int* flags, float* cnt0, int* nbr, int* slotmap,
        unsigned int* hashK, float* hashC, float* hashF, float* hashR,
        float* f0s, float* r0s, float* h1acc,
        int* arrive, int* release, float* out, int E) {
    int bid = blockIdx.x;
    int t = threadIdx.x;
    int gid = bid * NT + t;
    int idx64 = detect64(rowp);
    int nodeid = nodep[0];

    __shared__ float sm[16][DIM];

    // ====== Phase A: dense precompute + nodeid mark & first-touch slots ====
    // tiles: [0,512) U/V (16 embed rows); [512,1024) xw (16 x rows); 1024 cself
    for (int tile = bid; tile < 1025; tile += NB) {
        if (tile < 512) {
            int n0 = tile * 16;
            for (int i = t; i < 16 * DIM; i += NT)
                sm[i >> 7][i & 127] = embed[(size_t)n0 * DIM + i];
            __syncthreads();
            int sub = t >> 7;            // row group 0-7 / 8-15
            int q = (t >> 6) & 1;        // 0 -> U, 1 -> V
            int lane = t & 63;
            const float* Wc = W1e + (size_t)q * DIM * 64;
            float acc[8] = {0};
            for (int d = 0; d < DIM; d++) {
                float w = Wc[d * 64 + lane];
#pragma unroll
                for (int i = 0; i < 8; i++) acc[i] += sm[sub * 8 + i][d] * w;
            }
            float* o = q ? V : U;
            for (int i = 0; i < 8; i++)
                o[(size_t)(n0 + sub * 8 + i) * 64 + lane] = acc[i];
            __syncthreads();
        } else if (tile < 1024) {
            int n0 = (tile - 512) * 16;
            for (int i = t; i < 16 * DIM; i += NT)
                sm[i >> 7][i & 127] = x[(size_t)n0 * DIM + i];
            __syncthreads();
            int col = t & 127;
            int half = t >> 7;
            float acc[8] = {0};
            for (int d = 0; d < DIM; d++) {
                float w = Wg0[d * DIM + col];
#pragma unroll
                for (int i = 0; i < 8; i++) acc[i] += sm[half * 8 + i][d] * w;
            }
            for (int i = 0; i < 8; i++)
                xw[(size_t)(n0 + half * 8 + i) * DIM + col] = acc[i];
            __syncthreads();
        } else {
            if (t < DIM) sm[0][t] = embed[(size_t)nodeid * DIM + t];
            __syncthreads();
            if (t < 64) {
                float a = b1e[t];
                for (int d = 0; d < DIM; d++)
                    a += sm[0][d] * W1e[(2 * DIM + d) * 64 + t];
                cself[t] = a;
            }
            __syncthreads();
        }
    }
    // mark out-neighbors of nodeid; first-touch slot assignment
    // slotmap[] semantics: 0 = none, >0 = slot+1, -1 = claimed/overflow
    for (int e = gid; e < E; e += NB * NT) {
        int r = edge_idx(rowp, e, idx64);
        if (r != nodeid) continue;
        int c = edge_idx(colp, e, idx64);
        if (c == nodeid) continue;
        atomicAdd(&cnt0[c], adjd[e]);
        if (atomicCAS((unsigned int*)&slotmap[c], 0u, 0xFFFFFFFFu) == 0u) {
            int s = atomicAdd(&flags[1], 1);
            if (s < SMAX) {
                nbr[s] = c;
                __hip_atomic_store(&slotmap[c], s + 1, __ATOMIC_RELAXED,
                                   __HIP_MEMORY_SCOPE_AGENT);
            }
        }
    }
    gbar(arrive + 0 * NB * 32, release + 0 * 32, bid, t);

    // ====== Phase B: fused classify + gate MLP over all E edges ===========
    {
        float beta = tmp[0];
        float b2 = b2e[0];
        for (int e = gid; e < E; e += NB * NT) {
            int r = edge_idx(rowp, e, idx64);
            int c = edge_idx(colp, e, idx64);
            if (r == c) continue;
            int spr = slotmap[r];
            int spc = slotmap[c];
            bool fr = spr > 0, fc = spc > 0;
            if (!fr && !fc) continue;
            // per-thread gate MLP: la = relu(U[r]+V[c]+cself) . W2e + b2
            float la = b2;
            const float4* u4 = (const float4*)(U + (size_t)r * 64);
            const float4* v4 = (const float4*)(V + (size_t)c * 64);
            const float4* c4 = (const float4*)cself;
            const float4* w4 = (const float4*)W2e;
#pragma unroll
            for (int d = 0; d < 16; d++) {
                float4 uu = u4[d], vv = v4[d], cc = c4[d], ww = w4[d];
                float h0 = uu.x + vv.x + cc.x;
                float h1 = uu.y + vv.y + cc.y;
                float h2 = uu.z + vv.z + cc.z;
                float h3 = uu.w + vv.w + cc.w;
                la += (h0 > 0.f ? h0 : 0.f) * ww.x + (h1 > 0.f ? h1 : 0.f) * ww.y
                    + (h2 > 0.f ? h2 : 0.f) * ww.z + (h3 > 0.f ? h3 : 0.f) * ww.w;
            }
            float nz = noise[e];
            float gi = (logf(nz) - log1pf(-nz) + la) / beta;
            float v = 1.f / (1.f + expf(-gi));
            if (fr) {
                int sr = spr - 1;
                unsigned int key1 = ((unsigned int)(sr << 13) | (unsigned int)c) + 1u;
                int idx = hash_insert(hashK, key1);
                atomicAdd(&hashC[idx], adjd[e]);
                atomicAdd(&hashF[idx], v);
                if (c == nodeid) atomicAdd(&r0s[sr], v);
            }
            if (fc) {
                int sc = spc - 1;
                unsigned int key1 = ((unsigned int)(sc << 13) | (unsigned int)r) + 1u;
                int idx = hash_insert(hashK, key1);
                atomicAdd(&hashR[idx], v);
                if (r == nodeid) atomicAdd(&f0s[sc], v);
            }
        }
    }
    gbar(arrive + 1 * NB * 32, release + 1 * 32, bid, t);

    // ====== Phase C: hash-aggregate into h1acc ============================
    {
        int group = gid >> 7;                 // 128-thread groups
        int tg = t & 127;
        int ngroups = (NB * NT) >> 7;
        for (int entry = group; entry < HSIZE; entry += ngroups) {
            unsigned int key1 = hashK[entry];
            if (key1 == 0u) continue;
            float wgt = hashC[entry] * (hashF[entry] + hashR[entry]) * 0.5f;
            if (wgt == 0.f) continue;
            unsigned int key = key1 - 1u;
            int s = (int)(key >> 13);
            int k = (int)(key & 8191u);
            atomicAdd(&h1acc[(size_t)s * DIM + tg], wgt * xw[(size_t)k * DIM + tg]);
        }
    }
    gbar(arrive + 2 * NB * 32, release + 2 * 32, bid, t);

    // ====== Phase D: final reduce + softmax (block 0 only) ================
    if (bid != 0) return;
    __shared__ float sacc[7];
    if (t < 7) sacc[t] = 0.f;
    __syncthreads();
    int ns = flags[1]; if (ns > SMAX) ns = SMAX;
    int wave = t >> 6, lane = t & 63;
    for (int s = wave; s < ns; s += 4) {
        float a0 = cnt0[nbr[s]] * (f0s[s] + r0s[s]) * 0.5f;
        float v0 = h1acc[(size_t)s * DIM + lane];
        float v1 = h1acc[(size_t)s * DIM + lane + 64];
        v0 = v0 > 0.f ? v0 : 0.f;
        v1 = v1 > 0.f ? v1 : 0.f;
        float part[7];
        for (int c = 0; c < 7; c++) {
            float p = v0 * Wg1[lane * 7 + c] + v1 * Wg1[(lane + 64) * 7 + c];
            for (int o = 32; o >= 1; o >>= 1) p += __shfl_xor(p, o, 64);
            part[c] = p;
        }
        if (lane == 0)
            for (int c = 0; c < 7; c++) atomicAdd(&sacc[c], a0 * part[c]);
    }
    __syncthreads();
    if (t == 0) {
        float v[7], m = -1e30f, ssum = 0.f;
        for (int c = 0; c < 7; c++) { v[c] = sacc[c]; if (v[c] > m) m = v[c]; }
        for (int c = 0; c < 7; c++) { v[c] = expf(v[c] - m); ssum += v[c]; }
        for (int c = 0; c < 7; c++) out[c] = v[c] / ssum;
    }
}

extern "C" void kernel_launch(void* const* d_in, const int* in_sizes, int n_in,
                              void* d_out, int out_size, void* d_ws, size_t ws_size,
                              hipStream_t stream) {
    const float* x     = (const float*)d_in[0];
    const float* embed = (const float*)d_in[1];
    const float* adjd  = (const float*)d_in[2];
    const float* noise = (const float*)d_in[3];
    const float* tmp   = (const float*)d_in[4];
    const float* W1e   = (const float*)d_in[5];
    const float* b1e   = (const float*)d_in[6];
    const float* W2e   = (const float*)d_in[7];
    const float* b2e   = (const float*)d_in[8];
    const float* Wg0   = (const float*)d_in[9];
    const float* Wg1   = (const float*)d_in[10];
    const void*  rowp  = d_in[11];
    const void*  colp  = d_in[12];
    const int*   nodep = (const int*)d_in[13];
    int E = in_sizes[3];   // noise is float32[E]

    char* w = (char*)d_ws;
    size_t off = 0;
    auto alloc = [&](size_t bytes) -> char* {
        char* p = w + off;
        off = (off + bytes + 255) & ~(size_t)255;
        return p;
    };
    float*        cself   = (float*)alloc(64 * 4);
    int*          nbr     = (int*)  alloc(SMAX * 4);
    float*        U       = (float*)alloc((size_t)NNODES * 64 * 4);
    float*        V       = (float*)alloc((size_t)NNODES * 64 * 4);
    float*        xw      = (float*)alloc((size_t)NNODES * DIM * 4);
    char*         zstart  = w + off;
    int*          flags   = (int*)  alloc(256);
    int*          release = (int*)  alloc(NBAR * 32 * 4);
    int*          arrive  = (int*)  alloc((size_t)NBAR * NB * 32 * 4);
    int*          slotmap = (int*)  alloc((size_t)NNODES * 4);
    float*        cnt0    = (float*)alloc((size_t)NNODES * 4);
    float*        f0s     = (float*)alloc(SMAX * 4);
    float*        r0s     = (float*)alloc(SMAX * 4);
    unsigned int* hashK   = (unsigned int*)alloc((size_t)HSIZE * 4);
    float*        hashC   = (float*)alloc((size_t)HSIZE * 4);
    float*        hashF   = (float*)alloc((size_t)HSIZE * 4);
    float*        hashR   = (float*)alloc((size_t)HSIZE * 4);
    float*        h1acc   = (float*)alloc((size_t)SMAX * DIM * 4);
    size_t zbytes  = (size_t)((w + off) - zstart);
    int n4 = (int)(zbytes / 16);

    k_zero<<<(n4 + 255) / 256, 256, 0, stream>>>((float4*)zstart, n4);
    k_mega<<<NB, NT, 0, stream>>>(x, embed, adjd, noise, tmp, W1e, b1e, W2e, b2e,
                                  Wg0, Wg1, rowp, colp, nodep,
                                  U, V, xw, cself, flags, cnt0, nbr, slotmap,
                                  hashK, hashC, hashF, hashR, f0s, r0s,
                                  h1acc, arrive, release, (float*)d_out, E);
}

// Round 8
// 66.770 us; speedup vs baseline: 6.0114x; 1.2899x over previous
//
#include <hip/hip_runtime.h>
#include <hip/hip_bf16.h>
#include <math.h>

#define NNODES 8192
#define DIM 128
#define SMAX 128
#define HSIZE 16384   // hash table capacity (power of 2)
#define NB 256        // 1 block/CU -> co-resident
#define NT 1024       // 16 waves/CU = 4 waves/SIMD for latency hiding
#define TR 64         // rows per dense tile
#define NBAR 3

// Per-thread index-dtype detection: reads first 4 int64-interpretations of row.
__device__ __forceinline__ int detect64(const void* rowp) {
    const long long* p = (const long long*)rowp;
    int is64 = 1;
#pragma unroll
    for (int i = 0; i < 4; i++) {
        long long v = p[i];
        if (v < 0 || v >= NNODES) is64 = 0;
    }
    return is64;
}

__device__ __forceinline__ int edge_idx(const void* p, int e, int idx64) {
    if (idx64) return (int)((const long long*)p)[e];
    return ((const int*)p)[e];
}

__device__ __forceinline__ int hash_insert(unsigned int* hashK, unsigned int key1) {
    unsigned int h = (key1 * 2654435761u) & (HSIZE - 1);
    for (;;) {
        unsigned int prev = atomicCAS(&hashK[h], 0u, key1);
        if (prev == 0u || prev == key1) return (int)h;
        h = (h + 1) & (HSIZE - 1);
    }
}

// One-shot grid barrier with DISTRIBUTED arrival (pre-zeroed by k_zero).
// Single-counter agent fetch_add serializes (~44us/barrier @512 blocks, r6);
// distributed arrival + master-poll + single release flag is the fast form.
__device__ __forceinline__ void gbar(int* arrive, int* release, int bid, int t) {
    __syncthreads();
    if (bid == 0) {
        if (t > 0 && t < NB) {   // thread t waits for block t's arrival slot
            while (__hip_atomic_load(&arrive[t * 32], __ATOMIC_RELAXED,
                                     __HIP_MEMORY_SCOPE_AGENT) == 0)
                __builtin_amdgcn_s_sleep(1);
        }
        __syncthreads();
        __builtin_amdgcn_fence(__ATOMIC_ACQ_REL, "agent");
        if (t == 0)
            __hip_atomic_store(release, 1, __ATOMIC_RELAXED,
                               __HIP_MEMORY_SCOPE_AGENT);
        __syncthreads();
    } else {
        if (t == 0) {
            __builtin_amdgcn_fence(__ATOMIC_RELEASE, "agent");
            __hip_atomic_store(&arrive[bid * 32], 1, __ATOMIC_RELAXED,
                               __HIP_MEMORY_SCOPE_AGENT);
            while (__hip_atomic_load(release, __ATOMIC_RELAXED,
                                     __HIP_MEMORY_SCOPE_AGENT) == 0)
                __builtin_amdgcn_s_sleep(2);
            __builtin_amdgcn_fence(__ATOMIC_ACQUIRE, "agent");
        }
        __syncthreads();
    }
}

// --- K0: zero scratch (custom: rocclr fillBuffer is ~39us even for small) ---
__global__ __launch_bounds__(256) void k_zero(float4* z, int n4) {
    int i = blockIdx.x * blockDim.x + threadIdx.x;
    if (i < n4) z[i] = make_float4(0.f, 0.f, 0.f, 0.f);
}

// --- K1: whole pipeline, 4 phases, 3 distributed grid barriers ---
__global__ __launch_bounds__(NT) void k_mega(
        const float* x, const float* embed, const float* adjd, const float* noise,
        const float* tmp, const float* W1e, const float* b1e, const float* W2e,
        const float* b2e, const float* Wg0, const float* Wg1,
        const void* rowp, const void* colp, const int* nodep,
        float* U, float* V, float* xw, float* cself,
        int* flags, float* cnt0, int* nbr, int* slotmap,
        unsigned int* hashK, float* hashC, float* hashF, float* hashR,
        float* f0s, float* r0s, float* h1acc,
        int* arrive, int* release, float* out, int E) {
    int bid = blockIdx.x;
    int t = threadIdx.x;
    int gid = bid * NT + t;
    int idx64 = detect64(rowp);
    int nodeid = nodep[0];

    __shared__ float smf[TR * DIM];   // 32 KB

    // ====== Phase A: dense precompute + nodeid mark & first-touch slots ====
    // tiles: [0,128) U/V (64 embed rows each); [128,256) xw (64 x rows); 256 cself
    for (int tile = bid; tile < 257; tile += NB) {
        if (tile < 128) {
            int n0 = tile * TR;
            for (int i = t; i < TR * DIM; i += NT)
                smf[i] = embed[(size_t)n0 * DIM + i];
            __syncthreads();
            int half = (t >> 6) & 1;     // 0 -> U, 1 -> V (uniform per wave)
            int lane = t & 63;
            int rg = t >> 7;             // 0..7 -> rows rg*8 .. rg*8+7
            const float* Wc = W1e + (size_t)half * DIM * 64;
            float acc[8] = {0};
            for (int d = 0; d < DIM; d++) {
                float w = Wc[d * 64 + lane];
#pragma unroll
                for (int i = 0; i < 8; i++)
                    acc[i] += smf[(rg * 8 + i) * DIM + d] * w;   // LDS broadcast
            }
            float* o = half ? V : U;
            for (int i = 0; i < 8; i++)
                o[(size_t)(n0 + rg * 8 + i) * 64 + lane] = acc[i];
            __syncthreads();
        } else if (tile < 256) {
            int n0 = (tile - 128) * TR;
            for (int i = t; i < TR * DIM; i += NT)
                smf[i] = x[(size_t)n0 * DIM + i];
            __syncthreads();
            int col = t & 127;
            int rg = t >> 7;             // 0..7 -> rows rg*8 .. rg*8+7
            float acc[8] = {0};
            for (int d = 0; d < DIM; d++) {
                float w = Wg0[d * DIM + col];
#pragma unroll
                for (int i = 0; i < 8; i++)
                    acc[i] += smf[(rg * 8 + i) * DIM + d] * w;
            }
            for (int i = 0; i < 8; i++)
                xw[(size_t)(n0 + rg * 8 + i) * DIM + col] = acc[i];
            __syncthreads();
        } else {
            if (t < DIM) smf[t] = embed[(size_t)nodeid * DIM + t];
            __syncthreads();
            if (t < 64) {
                float a = b1e[t];
                for (int d = 0; d < DIM; d++)
                    a += smf[d] * W1e[(2 * DIM + d) * 64 + t];
                cself[t] = a;
            }
            __syncthreads();
        }
    }
    // mark out-neighbors of nodeid; first-touch slot assignment
    // slotmap[] semantics: 0 = none, >0 = slot+1, -1 = claimed/overflow
    for (int e = gid; e < E; e += NB * NT) {
        int r = edge_idx(rowp, e, idx64);
        if (r != nodeid) continue;
        int c = edge_idx(colp, e, idx64);
        if (c == nodeid) continue;
        atomicAdd(&cnt0[c], adjd[e]);
        if (atomicCAS((unsigned int*)&slotmap[c], 0u, 0xFFFFFFFFu) == 0u) {
            int s = atomicAdd(&flags[1], 1);
            if (s < SMAX) {
                nbr[s] = c;
                __hip_atomic_store(&slotmap[c], s + 1, __ATOMIC_RELAXED,
                                   __HIP_MEMORY_SCOPE_AGENT);
            }
        }
    }
    gbar(arrive + 0 * NB * 32, release + 0 * 32, bid, t);

    // ====== Phase B: fused classify + gate MLP over all E edges ===========
    {
        float beta = tmp[0];
        float b2 = b2e[0];
        for (int e = gid; e < E; e += NB * NT) {
            int r = edge_idx(rowp, e, idx64);
            int c = edge_idx(colp, e, idx64);
            if (r == c) continue;
            int spr = slotmap[r];
            int spc = slotmap[c];
            bool fr = spr > 0, fc = spc > 0;
            if (!fr && !fc) continue;
            // per-thread gate MLP: la = relu(U[r]+V[c]+cself) . W2e + b2
            float la = b2;
            const float4* u4 = (const float4*)(U + (size_t)r * 64);
            const float4* v4 = (const float4*)(V + (size_t)c * 64);
            const float4* c4 = (const float4*)cself;
            const float4* w4 = (const float4*)W2e;
#pragma unroll
            for (int d = 0; d < 16; d++) {
                float4 uu = u4[d], vv = v4[d], cc = c4[d], ww = w4[d];
                float h0 = uu.x + vv.x + cc.x;
                float h1 = uu.y + vv.y + cc.y;
                float h2 = uu.z + vv.z + cc.z;
                float h3 = uu.w + vv.w + cc.w;
                la += (h0 > 0.f ? h0 : 0.f) * ww.x + (h1 > 0.f ? h1 : 0.f) * ww.y
                    + (h2 > 0.f ? h2 : 0.f) * ww.z + (h3 > 0.f ? h3 : 0.f) * ww.w;
            }
            float nz = noise[e];
            float gi = (logf(nz) - log1pf(-nz) + la) / beta;
            float v = 1.f / (1.f + expf(-gi));
            if (fr) {
                int sr = spr - 1;
                unsigned int key1 = ((unsigned int)(sr << 13) | (unsigned int)c) + 1u;
                int idx = hash_insert(hashK, key1);
                atomicAdd(&hashC[idx], adjd[e]);
                atomicAdd(&hashF[idx], v);
                if (c == nodeid) atomicAdd(&r0s[sr], v);
            }
            if (fc) {
                int sc = spc - 1;
                unsigned int key1 = ((unsigned int)(sc << 13) | (unsigned int)r) + 1u;
                int idx = hash_insert(hashK, key1);
                atomicAdd(&hashR[idx], v);
                if (r == nodeid) atomicAdd(&f0s[sc], v);
            }
        }
    }
    gbar(arrive + 1 * NB * 32, release + 1 * 32, bid, t);

    // ====== Phase C: hash-aggregate into h1acc ============================
    {
        int group = gid >> 7;                 // 128-thread groups
        int tg = t & 127;
        int ngroups = (NB * NT) >> 7;
        for (int entry = group; entry < HSIZE; entry += ngroups) {
            unsigned int key1 = hashK[entry];
            if (key1 == 0u) continue;
            float wgt = hashC[entry] * (hashF[entry] + hashR[entry]) * 0.5f;
            if (wgt == 0.f) continue;
            unsigned int key = key1 - 1u;
            int s = (int)(key >> 13);
            int k = (int)(key & 8191u);
            atomicAdd(&h1acc[(size_t)s * DIM + tg], wgt * xw[(size_t)k * DIM + tg]);
        }
    }
    gbar(arrive + 2 * NB * 32, release + 2 * 32, bid, t);

    // ====== Phase D: final reduce + softmax (block 0 only) ================
    if (bid != 0) return;
    __shared__ float sacc[7];
    if (t < 7) sacc[t] = 0.f;
    __syncthreads();
    int ns = flags[1]; if (ns > SMAX) ns = SMAX;
    int wave = t >> 6, lane = t & 63;
    for (int s = wave; s < ns; s += 16) {
        float a0 = cnt0[nbr[s]] * (f0s[s] + r0s[s]) * 0.5f;
        float v0 = h1acc[(size_t)s * DIM + lane];
        float v1 = h1acc[(size_t)s * DIM + lane + 64];
        v0 = v0 > 0.f ? v0 : 0.f;
        v1 = v1 > 0.f ? v1 : 0.f;
        float part[7];
        for (int c = 0; c < 7; c++) {
            float p = v0 * Wg1[lane * 7 + c] + v1 * Wg1[(lane + 64) * 7 + c];
            for (int o = 32; o >= 1; o >>= 1) p += __shfl_xor(p, o, 64);
            part[c] = p;
        }
        if (lane == 0)
            for (int c = 0; c < 7; c++) atomicAdd(&sacc[c], a0 * part[c]);
    }
    __syncthreads();
    if (t == 0) {
        float v[7], m = -1e30f, ssum = 0.f;
        for (int c = 0; c < 7; c++) { v[c] = sacc[c]; if (v[c] > m) m = v[c]; }
        for (int c = 0; c < 7; c++) { v[c] = expf(v[c] - m); ssum += v[c]; }
        for (int c = 0; c < 7; c++) out[c] = v[c] / ssum;
    }
}

extern "C" void kernel_launch(void* const* d_in, const int* in_sizes, int n_in,
                              void* d_out, int out_size, void* d_ws, size_t ws_size,
                              hipStream_t stream) {
    const float* x     = (const float*)d_in[0];
    const float* embed = (const float*)d_in[1];
    const float* adjd  = (const float*)d_in[2];
    const float* noise = (const float*)d_in[3];
    const float* tmp   = (const float*)d_in[4];
    const float* W1e   = (const float*)d_in[5];
    const float* b1e   = (const float*)d_in[6];
    const float* W2e   = (const float*)d_in[7];
    const float* b2e   = (const float*)d_in[8];
    const float* Wg0   = (const float*)d_in[9];
    const float* Wg1   = (const float*)d_in[10];
    const void*  rowp  = d_in[11];
    const void*  colp  = d_in[12];
    const int*   nodep = (const int*)d_in[13];
    int E = in_sizes[3];   // noise is float32[E]

    char* w = (char*)d_ws;
    size_t off = 0;
    auto alloc = [&](size_t bytes) -> char* {
        char* p = w + off;
        off = (off + bytes + 255) & ~(size_t)255;
        return p;
    };
    float*        cself   = (float*)alloc(64 * 4);
    int*          nbr     = (int*)  alloc(SMAX * 4);
    float*        U       = (float*)alloc((size_t)NNODES * 64 * 4);
    float*        V       = (float*)alloc((size_t)NNODES * 64 * 4);
    float*        xw      = (float*)alloc((size_t)NNODES * DIM * 4);
    char*         zstart  = w + off;
    int*          flags   = (int*)  alloc(256);
    int*          release = (int*)  alloc(NBAR * 32 * 4);
    int*          arrive  = (int*)  alloc((size_t)NBAR * NB * 32 * 4);
    int*          slotmap = (int*)  alloc((size_t)NNODES * 4);
    float*        cnt0    = (float*)alloc((size_t)NNODES * 4);
    float*        f0s     = (float*)alloc(SMAX * 4);
    float*        r0s     = (float*)alloc(SMAX * 4);
    unsigned int* hashK   = (unsigned int*)alloc((size_t)HSIZE * 4);
    float*        hashC   = (float*)alloc((size_t)HSIZE * 4);
    float*        hashF   = (float*)alloc((size_t)HSIZE * 4);
    float*        hashR   = (float*)alloc((size_t)HSIZE * 4);
    float*        h1acc   = (float*)alloc((size_t)SMAX * DIM * 4);
    size_t zbytes  = (size_t)((w + off) - zstart);
    int n4 = (int)(zbytes / 16);

    k_zero<<<(n4 + 255) / 256, 256, 0, stream>>>((float4*)zstart, n4);
    k_mega<<<NB, NT, 0, stream>>>(x, embed, adjd, noise, tmp, W1e, b1e, W2e, b2e,
                                  Wg0, Wg1, rowp, colp, nodep,
                                  U, V, xw, cself, flags, cnt0, nbr, slotmap,
                                  hashK, hashC, hashF, hashR, f0s, r0s,
                                  h1acc, arrive, release, (float*)d_out, E);
}

// Round 9
// 64.060 us; speedup vs baseline: 6.2657x; 1.0423x over previous
//
#include <hip/hip_runtime.h>
#include <hip/hip_bf16.h>
#include <math.h>

#define NNODES 8192
#define DIM 128
#define SMAX 128
#define HSIZE 16384   // hash table capacity (power of 2)
#define NBD 256       // dense blocks (1/CU)
#define NTD 1024
#define NBS 256       // sparse blocks (1/CU, co-resident for grid barrier)
#define NTS 1024
#define NBAR 2

// Per-thread index-dtype detection: reads first 4 int64-interpretations of row.
__device__ __forceinline__ int detect64(const void* rowp) {
    const long long* p = (const long long*)rowp;
    int is64 = 1;
#pragma unroll
    for (int i = 0; i < 4; i++) {
        long long v = p[i];
        if (v < 0 || v >= NNODES) is64 = 0;
    }
    return is64;
}

__device__ __forceinline__ int edge_idx(const void* p, int e, int idx64) {
    if (idx64) return (int)((const long long*)p)[e];
    return ((const int*)p)[e];
}

__device__ __forceinline__ int hash_insert(unsigned int* hashK, unsigned int key1) {
    unsigned int h = (key1 * 2654435761u) & (HSIZE - 1);
    for (;;) {
        unsigned int prev = atomicCAS(&hashK[h], 0u, key1);
        if (prev == 0u || prev == key1) return (int)h;
        h = (h + 1) & (HSIZE - 1);
    }
}

// One-shot grid barrier with DISTRIBUTED arrival (slots pre-zeroed by k_zero).
// r6 lesson: single-counter agent fetch_add serializes (~44us @512 blocks).
// r8 lesson: broadcast LDS reads were the real phase-A cost, not this barrier.
__device__ __forceinline__ void gbar(int* arrive, int* release, int bid, int t) {
    __syncthreads();
    if (bid == 0) {
        if (t > 0 && t < NBS) {   // thread t waits for block t's arrival slot
            while (__hip_atomic_load(&arrive[t * 32], __ATOMIC_RELAXED,
                                     __HIP_MEMORY_SCOPE_AGENT) == 0)
                __builtin_amdgcn_s_sleep(1);
        }
        __syncthreads();
        __builtin_amdgcn_fence(__ATOMIC_ACQ_REL, "agent");
        if (t == 0)
            __hip_atomic_store(release, 1, __ATOMIC_RELAXED,
                               __HIP_MEMORY_SCOPE_AGENT);
        __syncthreads();
    } else {
        if (t == 0) {
            __builtin_amdgcn_fence(__ATOMIC_RELEASE, "agent");
            __hip_atomic_store(&arrive[bid * 32], 1, __ATOMIC_RELAXED,
                               __HIP_MEMORY_SCOPE_AGENT);
            while (__hip_atomic_load(release, __ATOMIC_RELAXED,
                                     __HIP_MEMORY_SCOPE_AGENT) == 0)
                __builtin_amdgcn_s_sleep(2);
            __builtin_amdgcn_fence(__ATOMIC_ACQUIRE, "agent");
        }
        __syncthreads();
    }
}

// --- K0: zero scratch (rocclr fillBuffer is ~39us even for small sizes) ---
__global__ __launch_bounds__(256) void k_zero(float4* z, int n4) {
    int i = blockIdx.x * blockDim.x + threadIdx.x;
    if (i < n4) z[i] = make_float4(0.f, 0.f, 0.f, 0.f);
}

// --- K1: dense precompute (U,V,xw,cself) + nodeid mark & slot assignment ---
// One 64-row tile per block. lane = output row (distinct LDS banks, stride 129);
// W batch loaded coalesced into lanes, broadcast via v_readlane (VALU pipe --
// NOT ds_bpermute/LDS pipe, and NOT per-lane broadcast ds_reads: r8's 40us bug).
__global__ __launch_bounds__(NTD) void k_dense(
        const float* embed, const float* x, const float* W1e, const float* b1e,
        const float* Wg0, const int* nodep, const void* rowp, const void* colp,
        const float* adjd,
        float* U, float* V, float* xw, float* cself,
        int* flags, float* cnt0, int* nbr, int* slotmap, int E) {
    int bid = blockIdx.x;
    int t = threadIdx.x;
    int w = t >> 6;
    int lane = t & 63;
    int nodeid = nodep[0];
    __shared__ float smf[64 * 129];   // padded: bank = (row + d) % 32
    __shared__ float semb[DIM];

    int tile = bid;
    const float* src = (tile < 128) ? embed + (size_t)tile * 64 * DIM
                                    : x + (size_t)(tile - 128) * 64 * DIM;
    for (int i = t; i < 64 * DIM; i += NTD)
        smf[(i >> 7) * 129 + (i & 127)] = src[i];
    if (bid == 255 && t < DIM) semb[t] = embed[(size_t)nodeid * DIM + t];
    __syncthreads();

    const float* Wsrc; int ldw, cb, doff;
    if (tile < 128) { Wsrc = W1e; ldw = 64;  doff = (w >> 3) * 128; cb = (w & 7) * 8; }
    else           { Wsrc = Wg0; ldw = DIM; doff = 0;              cb = w * 8; }

    int row = lane;
    float acc[8] = {0, 0, 0, 0, 0, 0, 0, 0};
    for (int d0 = 0; d0 < DIM; d0 += 8) {
        // lane l holds W[(doff+d0+(l>>3))*ldw + cb + (l&7)]  (coalesced-ish batch)
        float wb = Wsrc[(size_t)(doff + d0 + (lane >> 3)) * ldw + cb + (lane & 7)];
#pragma unroll
        for (int k = 0; k < 8; k++) {
            float a = smf[row * 129 + d0 + k];
#pragma unroll
            for (int j = 0; j < 8; j++) {
                float wv = __uint_as_float(
                    __builtin_amdgcn_readlane(__float_as_uint(wb), k * 8 + j));
                acc[j] = fmaf(a, wv, acc[j]);
            }
        }
    }
    if (tile < 128) {
        float* o = (w < 8) ? U : V;
        int n0 = tile * 64;
        *(float4*)&o[(size_t)(n0 + row) * 64 + cb] =
            make_float4(acc[0], acc[1], acc[2], acc[3]);
        *(float4*)&o[(size_t)(n0 + row) * 64 + cb + 4] =
            make_float4(acc[4], acc[5], acc[6], acc[7]);
    } else {
        int n0 = (tile - 128) * 64;
        *(float4*)&xw[(size_t)(n0 + row) * DIM + cb] =
            make_float4(acc[0], acc[1], acc[2], acc[3]);
        *(float4*)&xw[(size_t)(n0 + row) * DIM + cb + 4] =
            make_float4(acc[4], acc[5], acc[6], acc[7]);
    }
    // cself on block 255 wave 0
    if (bid == 255 && t < 64) {
        float a = b1e[t];
        for (int d = 0; d < DIM; d++)
            a += semb[d] * W1e[(size_t)(2 * DIM + d) * 64 + t];
        cself[t] = a;
    }
    // mark out-neighbors of nodeid; first-touch slot assignment
    // slotmap: 0 = none, >0 = slot+1, -1 = claimed/overflow
    int idx64 = detect64(rowp);
    for (int e = bid * NTD + t; e < E; e += NBD * NTD) {
        int r = edge_idx(rowp, e, idx64);
        if (r != nodeid) continue;
        int c = edge_idx(colp, e, idx64);
        if (c == nodeid) continue;
        atomicAdd(&cnt0[c], adjd[e]);
        if (atomicCAS((unsigned int*)&slotmap[c], 0u, 0xFFFFFFFFu) == 0u) {
            int s = atomicAdd(&flags[1], 1);
            if (s < SMAX) {
                nbr[s] = c;
                __hip_atomic_store(&slotmap[c], s + 1, __ATOMIC_RELAXED,
                                   __HIP_MEMORY_SCOPE_AGENT);
            }
        }
    }
}

// --- K2: sparse pipeline: gates -> bar -> aggregate -> bar -> final ---
__global__ __launch_bounds__(NTS) void k_sparse(
        const float* adjd, const float* noise, const float* tmp,
        const float* W2e, const float* b2e, const float* Wg1,
        const void* rowp, const void* colp, const int* nodep,
        const float* U, const float* V, const float* xw, const float* cself,
        int* flags, float* cnt0, int* nbr, int* slotmap,
        unsigned int* hashK, float* hashC, float* hashF, float* hashR,
        float* f0s, float* r0s, float* h1acc,
        int* arrive, int* release, float* out, int E) {
    int bid = blockIdx.x;
    int t = threadIdx.x;
    int gid = bid * NTS + t;
    int idx64 = detect64(rowp);
    int nodeid = nodep[0];

    // ====== Phase B: fused classify + gate MLP over all E edges ===========
    {
        float beta = tmp[0];
        float b2 = b2e[0];
        for (int e = gid; e < E; e += NBS * NTS) {
            int r = edge_idx(rowp, e, idx64);
            int c = edge_idx(colp, e, idx64);
            if (r == c) continue;
            int spr = slotmap[r];
            int spc = slotmap[c];
            bool fr = spr > 0, fc = spc > 0;
            if (!fr && !fc) continue;
            float la = b2;
            const float4* u4 = (const float4*)(U + (size_t)r * 64);
            const float4* v4 = (const float4*)(V + (size_t)c * 64);
            const float4* c4 = (const float4*)cself;
            const float4* w4 = (const float4*)W2e;
#pragma unroll
            for (int d = 0; d < 16; d++) {
                float4 uu = u4[d], vv = v4[d], cc = c4[d], ww = w4[d];
                float h0 = uu.x + vv.x + cc.x;
                float h1 = uu.y + vv.y + cc.y;
                float h2 = uu.z + vv.z + cc.z;
                float h3 = uu.w + vv.w + cc.w;
                la += (h0 > 0.f ? h0 : 0.f) * ww.x + (h1 > 0.f ? h1 : 0.f) * ww.y
                    + (h2 > 0.f ? h2 : 0.f) * ww.z + (h3 > 0.f ? h3 : 0.f) * ww.w;
            }
            float nz = noise[e];
            float gi = (logf(nz) - log1pf(-nz) + la) / beta;
            float v = 1.f / (1.f + expf(-gi));
            if (fr) {
                int sr = spr - 1;
                unsigned int key1 = ((unsigned int)(sr << 13) | (unsigned int)c) + 1u;
                int idx = hash_insert(hashK, key1);
                atomicAdd(&hashC[idx], adjd[e]);
                atomicAdd(&hashF[idx], v);
                if (c == nodeid) atomicAdd(&r0s[sr], v);
            }
            if (fc) {
                int sc = spc - 1;
                unsigned int key1 = ((unsigned int)(sc << 13) | (unsigned int)r) + 1u;
                int idx = hash_insert(hashK, key1);
                atomicAdd(&hashR[idx], v);
                if (r == nodeid) atomicAdd(&f0s[sc], v);
            }
        }
    }
    gbar(arrive + 0 * NBS * 32, release + 0 * 32, bid, t);

    // ====== Phase C: hash-aggregate into h1acc ============================
    {
        int group = gid >> 7;
        int tg = t & 127;
        int ngroups = (NBS * NTS) >> 7;
        for (int entry = group; entry < HSIZE; entry += ngroups) {
            unsigned int key1 = hashK[entry];
            if (key1 == 0u) continue;
            float wgt = hashC[entry] * (hashF[entry] + hashR[entry]) * 0.5f;
            if (wgt == 0.f) continue;
            unsigned int key = key1 - 1u;
            int s = (int)(key >> 13);
            int k = (int)(key & 8191u);
            atomicAdd(&h1acc[(size_t)s * DIM + tg], wgt * xw[(size_t)k * DIM + tg]);
        }
    }
    gbar(arrive + 1 * NBS * 32, release + 1 * 32, bid, t);

    // ====== Phase D: final reduce + softmax (block 0 only) ================
    if (bid != 0) return;
    __shared__ float sacc[7];
    if (t < 7) sacc[t] = 0.f;
    __syncthreads();
    int ns = flags[1]; if (ns > SMAX) ns = SMAX;
    int wave = t >> 6, lane = t & 63;
    for (int s = wave; s < ns; s += 16) {
        float a0 = cnt0[nbr[s]] * (f0s[s] + r0s[s]) * 0.5f;
        float v0 = h1acc[(size_t)s * DIM + lane];
        float v1 = h1acc[(size_t)s * DIM + lane + 64];
        v0 = v0 > 0.f ? v0 : 0.f;
        v1 = v1 > 0.f ? v1 : 0.f;
        float part[7];
        for (int c = 0; c < 7; c++) {
            float p = v0 * Wg1[lane * 7 + c] + v1 * Wg1[(lane + 64) * 7 + c];
            for (int o = 32; o >= 1; o >>= 1) p += __shfl_xor(p, o, 64);
            part[c] = p;
        }
        if (lane == 0)
            for (int c = 0; c < 7; c++) atomicAdd(&sacc[c], a0 * part[c]);
    }
    __syncthreads();
    if (t == 0) {
        float v[7], m = -1e30f, ssum = 0.f;
        for (int c = 0; c < 7; c++) { v[c] = sacc[c]; if (v[c] > m) m = v[c]; }
        for (int c = 0; c < 7; c++) { v[c] = expf(v[c] - m); ssum += v[c]; }
        for (int c = 0; c < 7; c++) out[c] = v[c] / ssum;
    }
}

extern "C" void kernel_launch(void* const* d_in, const int* in_sizes, int n_in,
                              void* d_out, int out_size, void* d_ws, size_t ws_size,
                              hipStream_t stream) {
    const float* x     = (const float*)d_in[0];
    const float* embed = (const float*)d_in[1];
    const float* adjd  = (const float*)d_in[2];
    const float* noise = (const float*)d_in[3];
    const float* tmp   = (const float*)d_in[4];
    const float* W1e   = (const float*)d_in[5];
    const float* b1e   = (const float*)d_in[6];
    const float* W2e   = (const float*)d_in[7];
    const float* b2e   = (const float*)d_in[8];
    const float* Wg0   = (const float*)d_in[9];
    const float* Wg1   = (const float*)d_in[10];
    const void*  rowp  = d_in[11];
    const void*  colp  = d_in[12];
    const int*   nodep = (const int*)d_in[13];
    int E = in_sizes[3];   // noise is float32[E]

    char* w = (char*)d_ws;
    size_t off = 0;
    auto alloc = [&](size_t bytes) -> char* {
        char* p = w + off;
        off = (off + bytes + 255) & ~(size_t)255;
        return p;
    };
    float*        cself   = (float*)alloc(64 * 4);
    int*          nbr     = (int*)  alloc(SMAX * 4);
    float*        U       = (float*)alloc((size_t)NNODES * 64 * 4);
    float*        V       = (float*)alloc((size_t)NNODES * 64 * 4);
    float*        xw      = (float*)alloc((size_t)NNODES * DIM * 4);
    char*         zstart  = w + off;
    int*          flags   = (int*)  alloc(256);
    int*          release = (int*)  alloc(NBAR * 32 * 4);
    int*          arrive  = (int*)  alloc((size_t)NBAR * NBS * 32 * 4);
    int*          slotmap = (int*)  alloc((size_t)NNODES * 4);
    float*        cnt0    = (float*)alloc((size_t)NNODES * 4);
    float*        f0s     = (float*)alloc(SMAX * 4);
    float*        r0s     = (float*)alloc(SMAX * 4);
    unsigned int* hashK   = (unsigned int*)alloc((size_t)HSIZE * 4);
    float*        hashC   = (float*)alloc((size_t)HSIZE * 4);
    float*        hashF   = (float*)alloc((size_t)HSIZE * 4);
    float*        hashR   = (float*)alloc((size_t)HSIZE * 4);
    float*        h1acc   = (float*)alloc((size_t)SMAX * DIM * 4);
    size_t zbytes  = (size_t)((w + off) - zstart);
    int n4 = (int)(zbytes / 16);

    k_zero<<<(n4 + 255) / 256, 256, 0, stream>>>((float4*)zstart, n4);
    k_dense<<<NBD, NTD, 0, stream>>>(embed, x, W1e, b1e, Wg0, nodep, rowp, colp,
                                     adjd, U, V, xw, cself, flags, cnt0, nbr,
                                     slotmap, E);
    k_sparse<<<NBS, NTS, 0, stream>>>(adjd, noise, tmp, W2e, b2e, Wg1,
                                      rowp, colp, nodep, U, V, xw, cself,
                                      flags, cnt0, nbr, slotmap,
                                      hashK, hashC, hashF, hashR, f0s, r0s,
                                      h1acc, arrive, release, (float*)d_out, E);
}